// Round 1
// baseline (14474.780 us; speedup 1.0000x reference)
//
#include <hip/hip_runtime.h>

// LSTM: T=16384 steps, B=32 batches, H=96 hidden, gates 4H=384.
// One workgroup per batch (32 blocks); 384 threads = 6 waves.
// Thread g owns row g of w_hh (96 floats in VGPRs). h broadcast via LDS.
// Two barriers per step: gates->act_s (bar1), c/h update->h_s (bar2).
// Output projection reduced with wave shuffles, stored one step deferred.

constexpr int HH = 96;     // hidden
constexpr int GG = 384;    // 4*H gates
constexpr int BB = 32;     // batch
constexpr int TT = 16384;  // timesteps
constexpr int CH = 2048;   // x chunk in LDS (8 KB)

__launch_bounds__(GG, 1)
__global__ void lstm_kernel(const float* __restrict__ x,
                            const float* __restrict__ w_ih,
                            const float* __restrict__ w_hh,
                            const float* __restrict__ b_ih,
                            const float* __restrict__ b_hh,
                            const float* __restrict__ fc_w,
                            const float* __restrict__ fc_b,
                            float* __restrict__ out) {
    __shared__ float xs[CH];
    __shared__ float act_s[GG];
    __shared__ float h_s[HH];
    __shared__ float red_s[2];

    const int g = threadIdx.x;   // gate row 0..383
    const int b = blockIdx.x;    // batch 0..31

    // Load this thread's w_hh row into registers (one-time, latency amortized).
    float4 W4[24];
    const float4* wrow = reinterpret_cast<const float4*>(w_hh + g * HH);
#pragma unroll
    for (int kk = 0; kk < 24; ++kk) W4[kk] = wrow[kk];

    const float wih_g  = w_ih[g];
    const float bias_g = b_ih[g] + b_hh[g];

    // Branchless activation: sigmoid(x)=1/(1+e^-x); tanh(x)=2/(1+e^-2x)-1.
    // gates order: i[0:96) f[96:192) g[192:288) o[288:384)
    const bool is_tanh = (g >= 2 * HH && g < 3 * HH);
    const float a_scale = is_tanh ? 2.0f : 1.0f;
    const float a_mul   = is_tanh ? 2.0f : 1.0f;
    const float a_add   = is_tanh ? -1.0f : 0.0f;

    float c = 0.0f;
    const float fcw_j = (g < HH) ? fc_w[g] : 0.0f;
    const float fcb   = fc_b[0];

    if (g < HH) h_s[g] = 0.0f;
    float x_prev = 0.0f;
    __syncthreads();

    for (int t = 0; t < TT; ++t) {
        // Refill x chunk every CH steps (readers of old chunk are past bar2).
        if ((t & (CH - 1)) == 0) {
            for (int i = g; i < CH; i += GG) xs[i] = x[(t + i) * BB + b];
            __syncthreads();
        }
        const float xv = xs[t & (CH - 1)];

        // Deferred output store for step t-1 (red_s valid: written before bar2,
        // next overwrite only after bar1 of this step).
        if (g == 128) {
            if (t > 0) out[(t - 1) * BB + b] = red_s[0] + red_s[1] + fcb + x_prev;
            x_prev = xv;
        }

        // ---- Phase A: gate matvec (reads h_s, writes act_s) ----
        float acc = fmaf(xv, wih_g, bias_g);
        const float4* h4 = reinterpret_cast<const float4*>(h_s);
#pragma unroll
        for (int kk = 0; kk < 24; ++kk) {
            const float4 hv = h4[kk];   // uniform address -> LDS broadcast
            const float4 wv = W4[kk];
            acc = fmaf(wv.x, hv.x, acc);
            acc = fmaf(wv.y, hv.y, acc);
            acc = fmaf(wv.z, hv.z, acc);
            acc = fmaf(wv.w, hv.w, acc);
        }
        const float s = __builtin_amdgcn_rcpf(1.0f + __expf(-acc * a_scale));
        act_s[g] = fmaf(s, a_mul, a_add);
        __syncthreads();   // bar1: act_s ready

        // ---- Phase B: c/h update + output partial reduce (waves 0,1) ----
        if (g < 128) {
            float p = 0.0f;
            if (g < HH) {
                const float iv = act_s[g];
                const float fv = act_s[HH + g];
                const float gv = act_s[2 * HH + g];
                const float ov = act_s[3 * HH + g];
                c = fmaf(fv, c, iv * gv);
                const float th =
                    fmaf(2.0f, __builtin_amdgcn_rcpf(1.0f + __expf(-2.0f * c)), -1.0f);
                const float h = ov * th;
                h_s[g] = h;
                p = h * fcw_j;
            }
#pragma unroll
            for (int off = 32; off > 0; off >>= 1) p += __shfl_down(p, off);
            if ((g & 63) == 0) red_s[g >> 6] = p;
        }
        __syncthreads();   // bar2: h_s + red_s ready
    }
    // Final deferred store (red_s for t = TT-1 is valid after last bar2).
    if (g == 128) out[(TT - 1) * BB + b] = red_s[0] + red_s[1] + fcb + x_prev;
}

extern "C" void kernel_launch(void* const* d_in, const int* in_sizes, int n_in,
                              void* d_out, int out_size, void* d_ws, size_t ws_size,
                              hipStream_t stream) {
    const float* x    = (const float*)d_in[0];
    const float* w_ih = (const float*)d_in[1];
    const float* w_hh = (const float*)d_in[2];
    const float* b_ih = (const float*)d_in[3];
    const float* b_hh = (const float*)d_in[4];
    const float* fc_w = (const float*)d_in[5];
    const float* fc_b = (const float*)d_in[6];
    float* out = (float*)d_out;

    lstm_kernel<<<dim3(BB), dim3(GG), 0, stream>>>(x, w_ih, w_hh, b_ih, b_hh,
                                                   fc_w, fc_b, out);
}